// Round 3
// baseline (9502.290 us; speedup 1.0000x reference)
//
#include <hip/hip_runtime.h>
#include <hip/hip_cooperative_groups.h>

namespace cg = cooperative_groups;

typedef unsigned short u16;
typedef unsigned int u32;
typedef __bf16 bfx8 __attribute__((ext_vector_type(8)));
typedef float f32x4 __attribute__((ext_vector_type(4)));

constexpr int BB = 64;     // batch
constexpr int TT = 64;     // time
constexpr int EE = 2048;   // x feature
constexpr int DD = 4096;   // deter
constexpr int GG = 8;      // groups
constexpr int H3 = 3 * DD;       // 12288
constexpr int CH = H3 / GG;      // 1536
constexpr float EPSf = 1e-4f;
constexpr int LSC = 72;          // 64 + 8 bf16 pad

static __device__ __forceinline__ u16 f2bf(float f) {
  u32 u = __builtin_bit_cast(u32, f);
  u32 r = (u + 0x7fffu + ((u >> 16) & 1u)) >> 16;
  return (u16)r;
}

// ---------------- prepass kernels ----------------

__global__ void __launch_bounds__(256) k_f2b(const float* __restrict__ in,
                                             u16* __restrict__ out, int n4) {
  int i = blockIdx.x * 256 + threadIdx.x;
  int stride = gridDim.x * 256;
  for (; i < n4; i += stride) {
    float4 v = ((const float4*)in)[i];
    uint2 o;
    o.x = (u32)f2bf(v.x) | ((u32)f2bf(v.y) << 16);
    o.y = (u32)f2bf(v.z) | ((u32)f2bf(v.w) << 16);
    ((uint2*)out)[i] = o;
  }
}

__global__ void __launch_bounds__(256) k_initdet(const float* __restrict__ d0,
                                                 float* __restrict__ dF,
                                                 u16* __restrict__ dB, int n4) {
  int i = blockIdx.x * 256 + threadIdx.x;
  if (i < n4) {
    float4 v = ((const float4*)d0)[i];
    ((float4*)dF)[i] = v;
    uint2 o;
    o.x = (u32)f2bf(v.x) | ((u32)f2bf(v.y) << 16);
    o.y = (u32)f2bf(v.z) | ((u32)f2bf(v.w) << 16);
    ((uint2*)dB)[i] = o;
  }
}

// in [R][C] f32 -> out [C][R] bf16  (batched over blockIdx.z)
__global__ void __launch_bounds__(256) k_transpose_f2b(const float* __restrict__ in,
                                                       u16* __restrict__ out,
                                                       int R, int C) {
  __shared__ float tile[32][33];
  size_t base = (size_t)blockIdx.z * R * C;
  in += base; out += base;
  int tx = threadIdx.x & 31, ty = threadIdx.x >> 5;
  int r0 = blockIdx.y * 32, c0 = blockIdx.x * 32;
#pragma unroll
  for (int i = 0; i < 4; i++) {
    int rr = ty * 4 + i;
    tile[rr][tx] = in[(size_t)(r0 + rr) * C + (c0 + tx)];
  }
  __syncthreads();
#pragma unroll
  for (int i = 0; i < 4; i++) {
    int cc = ty * 4 + i;
    out[(size_t)(c0 + cc) * R + (r0 + tx)] = f2bf(tile[tx][cc]);
  }
}

// ---------------- GEMM for P1 (Xproj): A[m][k] bf16 x B[n][k] bf16 -> C f32 ----------------

template<int BM, int BN, int WR, int WC>
__global__ void __launch_bounds__(256) k_gemm(
    const u16* __restrict__ A, int lda,
    const u16* __restrict__ B, int ldb,
    float* __restrict__ C, int ldc,
    const float* __restrict__ bias,
    int K) {
  constexpr int BK = 64, LS = BK + 8;
  constexpr int WTM = BM / WR, WTN = BN / WC, MF = WTM / 16, NF = WTN / 16;
  __shared__ u16 As[BM * LS];
  __shared__ u16 Bs[BN * LS];
  const int tid = threadIdx.x;
  const int m0 = blockIdx.y * BM, n0 = blockIdx.x * BN;
  const int w = tid >> 6, lane = tid & 63;
  const int wr = w / WC, wc = w % WC;
  const int lr = lane & 15, lk = (lane >> 4) * 8;

  f32x4 acc[MF][NF] = {};

  for (int kt = 0; kt < K; kt += BK) {
#pragma unroll
    for (int c = tid; c < BM * 8; c += 256) {
      int row = c >> 3, cc = c & 7;
      *(uint4*)&As[row * LS + cc * 8] =
          *(const uint4*)(A + (size_t)(m0 + row) * lda + kt + cc * 8);
    }
#pragma unroll
    for (int c = tid; c < BN * 8; c += 256) {
      int row = c >> 3, cc = c & 7;
      *(uint4*)&Bs[row * LS + cc * 8] =
          *(const uint4*)(B + (size_t)(n0 + row) * ldb + kt + cc * 8);
    }
    __syncthreads();
#pragma unroll
    for (int kk = 0; kk < BK; kk += 32) {
      bfx8 av[MF], bv[NF];
#pragma unroll
      for (int mi = 0; mi < MF; mi++)
        av[mi] = *(const bfx8*)&As[(wr * WTM + mi * 16 + lr) * LS + kk + lk];
#pragma unroll
      for (int ni = 0; ni < NF; ni++)
        bv[ni] = *(const bfx8*)&Bs[(wc * WTN + ni * 16 + lr) * LS + kk + lk];
#pragma unroll
      for (int mi = 0; mi < MF; mi++)
#pragma unroll
        for (int ni = 0; ni < NF; ni++)
          acc[mi][ni] = __builtin_amdgcn_mfma_f32_16x16x32_bf16(av[mi], bv[ni], acc[mi][ni], 0, 0, 0);
    }
    __syncthreads();
  }

  const int rq = (lane >> 4) * 4;
#pragma unroll
  for (int mi = 0; mi < MF; mi++) {
#pragma unroll
    for (int ni = 0; ni < NF; ni++) {
      int n = n0 + wc * WTN + ni * 16 + lr;
      float bias_v = bias ? bias[n] : 0.f;
#pragma unroll
      for (int r = 0; r < 4; r++) {
        int m = m0 + wr * WTM + mi * 16 + rq + r;
        C[(size_t)m * ldc + n] = acc[mi][ni][r] + bias_v;
      }
    }
  }
}

// ---------------- scan phase device functions (shared by coop + fallback) ----------------

struct ScanPtrs {
  const u16* WT;       // [4096][6144]
  const u16* WbT;      // [8][1536][512]
  const float* Xproj;  // [B*T][D]
  const float* scale_in;
  const float* b_blk;
  const float* sblk;
  float* part;         // [4][64][4096]
  u16* ybf;            // [64][4096]
  float* zbuf;         // [64][12288]
  float* zsq;          // [192][64]
  float* dF;           // [64][4096]
  u16* dB;             // [64][4096]
  float* out;          // [B][T][D]
};

// Phase A: part[kc] = deter_bf @ W1[:, k-slice]   (256 WGs = 64 n-tiles x 4 k-splits)
__device__ __forceinline__ void phaseA(int wg, int tid, const ScanPtrs& P,
                                       u16* As, u16* Bs) {
  const int w = tid >> 6, lane = tid & 63;
  const int lr = lane & 15, lk = (lane >> 4) * 8, rq = (lane >> 4) * 4;
  const int n0 = (wg & 63) * 64;
  const int kc = wg >> 6;                 // 0..3
  const int k0 = kc * 1024;
  const int wr = w >> 1, wc = w & 1;      // 4 M-waves x 2 N-waves
  const int srow = tid >> 3, scc = (tid & 7) * 8;
  f32x4 acc[2] = {};
  for (int kt = 0; kt < 1024; kt += 64) {
    *(uint4*)&As[srow * LSC + scc] =
        *(const uint4*)(P.dB + (size_t)srow * DD + k0 + kt + scc);
    *(uint4*)&Bs[srow * LSC + scc] =
        *(const uint4*)(P.WT + (size_t)(n0 + srow) * (DD + EE) + k0 + kt + scc);
    __syncthreads();
#pragma unroll
    for (int kk = 0; kk < 64; kk += 32) {
      bfx8 av = *(const bfx8*)&As[(wr * 16 + lr) * LSC + kk + lk];
#pragma unroll
      for (int ni = 0; ni < 2; ni++) {
        bfx8 bv = *(const bfx8*)&Bs[(wc * 32 + ni * 16 + lr) * LSC + kk + lk];
        acc[ni] = __builtin_amdgcn_mfma_f32_16x16x32_bf16(av, bv, acc[ni], 0, 0, 0);
      }
    }
    __syncthreads();
  }
  float* Pp = P.part + (size_t)kc * BB * DD;
#pragma unroll
  for (int ni = 0; ni < 2; ni++)
#pragma unroll
    for (int r = 0; r < 4; r++)
      Pp[(size_t)(wr * 16 + rq + r) * DD + n0 + wc * 32 + ni * 16 + lr] = acc[ni][r];
}

// Phase B: y = silu(rms(sum(part)+Xproj_t) * scale_in)   (WGs 0..63 = batch row)
__device__ __forceinline__ void phaseB(int b, int tid, int t, const ScanPtrs& P,
                                       float* sred) {
  const int w = tid >> 6, lane = tid & 63;
  const float* xp = P.Xproj + ((size_t)b * TT + t) * DD;
  float v[8];
  float ss = 0.f;
#pragma unroll
  for (int j = 0; j < 2; j++) {
    const int n = tid * 8 + j * 4;
    float4 a = *(const float4*)(xp + n);
#pragma unroll
    for (int kc = 0; kc < 4; kc++) {
      float4 p = *(const float4*)(P.part + (size_t)kc * BB * DD + (size_t)b * DD + n);
      a.x += p.x; a.y += p.y; a.z += p.z; a.w += p.w;
    }
    v[j * 4] = a.x; v[j * 4 + 1] = a.y; v[j * 4 + 2] = a.z; v[j * 4 + 3] = a.w;
    ss += a.x * a.x + a.y * a.y + a.z * a.z + a.w * a.w;
  }
#pragma unroll
  for (int o = 32; o > 0; o >>= 1) ss += __shfl_down(ss, o);
  if (lane == 0) sred[w] = ss;
  __syncthreads();
  float tot = 0.f;
#pragma unroll
  for (int i = 0; i < 8; i++) tot += sred[i];
  const float r = rsqrtf(tot / (float)DD + EPSf);
#pragma unroll
  for (int j = 0; j < 8; j++) {
    const int n = tid * 8 + j;
    float yv = v[j] * r * P.scale_in[n];
    yv = yv / (1.f + __expf(-yv));
    P.ybf[(size_t)b * DD + n] = f2bf(yv);
  }
}

// Phase C: z = blockdiag(y @ Wblk) + b_blk, fused per-row sumsq partials
// (WGs 0..191, each 64 global z-cols)
__device__ __forceinline__ void phaseC(int wg, int tid, const ScanPtrs& P,
                                       u16* As, u16* Bs, float* sqP) {
  const int w = tid >> 6, lane = tid & 63;
  const int lr = lane & 15, lk = (lane >> 4) * 8, rq = (lane >> 4) * 4;
  const int n0g = wg * 64;
  const int g = n0g / CH, nl = n0g % CH;
  const u16* Ap = P.ybf + g * (DD / GG);
  const u16* Bp = P.WbT + ((size_t)g * CH + nl) * (DD / GG);
  const int wr = w >> 1, wc = w & 1;
  const int srow = tid >> 3, scc = (tid & 7) * 8;
  f32x4 acc[2] = {};
  for (int kt = 0; kt < DD / GG; kt += 64) {
    *(uint4*)&As[srow * LSC + scc] =
        *(const uint4*)(Ap + (size_t)srow * DD + kt + scc);
    *(uint4*)&Bs[srow * LSC + scc] =
        *(const uint4*)(Bp + (size_t)srow * (DD / GG) + kt + scc);
    __syncthreads();
#pragma unroll
    for (int kk = 0; kk < 64; kk += 32) {
      bfx8 av = *(const bfx8*)&As[(wr * 16 + lr) * LSC + kk + lk];
#pragma unroll
      for (int ni = 0; ni < 2; ni++) {
        bfx8 bv = *(const bfx8*)&Bs[(wc * 32 + ni * 16 + lr) * LSC + kk + lk];
        acc[ni] = __builtin_amdgcn_mfma_f32_16x16x32_bf16(av, bv, acc[ni], 0, 0, 0);
      }
    }
    __syncthreads();
  }
  float sq[4] = {0.f, 0.f, 0.f, 0.f};
#pragma unroll
  for (int ni = 0; ni < 2; ni++) {
    const int n = n0g + wc * 32 + ni * 16 + lr;
    const float bias_v = P.b_blk[n];
#pragma unroll
    for (int r = 0; r < 4; r++) {
      const float zv = acc[ni][r] + bias_v;
      P.zbuf[(size_t)(wr * 16 + rq + r) * H3 + n] = zv;
      sq[r] += zv * zv;
    }
  }
#pragma unroll
  for (int o = 1; o < 16; o <<= 1) {
#pragma unroll
    for (int r = 0; r < 4; r++) sq[r] += __shfl_xor(sq[r], o);
  }
  if (lr == 0) {
#pragma unroll
    for (int r = 0; r < 4; r++) sqP[w * 16 + rq + r] = sq[r];  // wave w covers rows wr*16..+16, half wc
  }
  __syncthreads();
  if (tid < 64) {
    const int m = tid;
    P.zsq[(size_t)wg * 64 + m] =
        sqP[((m >> 4) * 2) * 16 + (m & 15)] + sqP[((m >> 4) * 2 + 1) * 16 + (m & 15)];
  }
}

// Phase D: block-rms + gates + deter update + out write  (256 WGs = 64 b x 4 col-slices)
__device__ __forceinline__ void phaseD(int wg, int tid, int t, const ScanPtrs& P,
                                       float* sred) {
  const int b = wg >> 2, s = wg & 3;
  if (tid < 8) {
    float ssq = 0.f;
    const int j0 = tid * 24;
#pragma unroll
    for (int j = 0; j < 24; j++) ssq += P.zsq[(size_t)(j0 + j) * 64 + b];
    sred[tid] = rsqrtf(ssq / (float)CH + EPSf);
  }
  __syncthreads();
  const int d0 = s * 1024 + tid * 2;
  const float* zr = P.zbuf + (size_t)b * H3;
  float2 z0 = *(const float2*)(zr + d0);
  float2 z1 = *(const float2*)(zr + DD + d0);
  float2 z2 = *(const float2*)(zr + 2 * DD + d0);
  float2 dold = *(const float2*)(P.dF + (size_t)b * DD + d0);
  const float rsA = sred[d0 / CH];
  const float rsB = sred[(DD + d0) / CH];
  const float rsC = sred[(2 * DD + d0) / CH];
  float dn[2];
#pragma unroll
  for (int e = 0; e < 2; e++) {
    const int dd = d0 + e;
    const float a0 = (e ? z0.y : z0.x) * rsA * P.sblk[dd];
    const float a1 = (e ? z1.y : z1.x) * rsB * P.sblk[DD + dd];
    const float a2 = (e ? z2.y : z2.x) * rsC * P.sblk[2 * DD + dd];
    const float reset = 1.f / (1.f + __expf(-a0));
    const float cand = tanhf(reset * a1);
    const float upd = 1.f / (1.f + __expf(-(a2 - 1.f)));
    dn[e] = upd * cand + (1.f - upd) * ((e ? dold.y : dold.x));
  }
  *(float2*)(P.dF + (size_t)b * DD + d0) = make_float2(dn[0], dn[1]);
  *(u32*)(P.dB + (size_t)b * DD + d0) = (u32)f2bf(dn[0]) | ((u32)f2bf(dn[1]) << 16);
  *(float2*)(P.out + ((size_t)b * TT + t) * DD + d0) = make_float2(dn[0], dn[1]);
}

// ---------------- cooperative persistent scan: 256 WGs x 512 threads (1 WG/CU) ----------------

__global__ void __launch_bounds__(512, 2) k_scan(ScanPtrs P) {
  cg::grid_group grid = cg::this_grid();
  __shared__ u16 As[64 * LSC];
  __shared__ u16 Bs[64 * LSC];
  __shared__ float sred[8];
  __shared__ float sqP[128];
  const int wg = blockIdx.x, tid = threadIdx.x;
  for (int t = 0; t < TT; ++t) {
    phaseA(wg, tid, P, As, Bs);
    grid.sync();
    if (wg < BB) phaseB(wg, tid, t, P, sred);
    grid.sync();
    if (wg < 192) phaseC(wg, tid, P, As, Bs, sqP);
    grid.sync();
    phaseD(wg, tid, t, P, sred);
    grid.sync();
  }
}

// ---------------- fallback per-phase kernels (used if cooperative launch is rejected) ----------------

__global__ void __launch_bounds__(512, 2) kA(ScanPtrs P) {
  __shared__ u16 As[64 * LSC];
  __shared__ u16 Bs[64 * LSC];
  phaseA(blockIdx.x, threadIdx.x, P, As, Bs);
}
__global__ void __launch_bounds__(512, 2) kB(ScanPtrs P, int t) {
  __shared__ float sred[8];
  phaseB(blockIdx.x, threadIdx.x, t, P, sred);
}
__global__ void __launch_bounds__(512, 2) kC(ScanPtrs P) {
  __shared__ u16 As[64 * LSC];
  __shared__ u16 Bs[64 * LSC];
  __shared__ float sqP[128];
  phaseC(blockIdx.x, threadIdx.x, P, As, Bs, sqP);
}
__global__ void __launch_bounds__(512, 2) kD(ScanPtrs P, int t) {
  __shared__ float sred[8];
  phaseD(blockIdx.x, threadIdx.x, t, P, sred);
}

// ---------------- host ----------------

extern "C" void kernel_launch(void* const* d_in, const int* in_sizes, int n_in,
                              void* d_out, int out_size, void* d_ws, size_t ws_size,
                              hipStream_t stream) {
  (void)in_sizes; (void)n_in; (void)out_size; (void)ws_size;
  const float* x         = (const float*)d_in[0];  // [B,T,E]
  const float* deter0    = (const float*)d_in[1];  // [B,D]
  const float* W_in      = (const float*)d_in[2];  // [D+E, D]
  const float* b_in      = (const float*)d_in[3];  // [D]
  const float* scale_in  = (const float*)d_in[4];  // [D]
  const float* W_blk     = (const float*)d_in[5];  // [G, D/G, 3D/G]
  const float* b_blk     = (const float*)d_in[6];  // [3D]
  const float* scale_blk = (const float*)d_in[7];  // [G, 3D/G]
  float* out = (float*)d_out;

  char* ws = (char*)d_ws;
  size_t off = 0;
  auto alloc = [&](size_t bytes) -> void* {
    void* p = ws + off;
    off += (bytes + 255) & ~(size_t)255;
    return p;
  };
  u16*   WT    = (u16*)alloc((size_t)DD * (DD + EE) * 2);       // 50.3 MB
  u16*   WbT   = (u16*)alloc((size_t)GG * CH * (DD / GG) * 2);  // 12.6 MB
  float* Xproj = (float*)alloc((size_t)BB * TT * DD * 4);       // 64 MB
  float* dF    = (float*)alloc((size_t)BB * DD * 4);            // 1 MB
  u16*   dB    = (u16*)alloc((size_t)BB * DD * 2);              // 0.5 MB
  // scratch region: xbf (prepass/P1 only) aliases scan-only buffers
  char* scratch = (char*)alloc((size_t)BB * TT * EE * 2);       // 16.8 MB
  u16*   xbf  = (u16*)scratch;
  float* part = (float*)scratch;                                // 4 MB
  size_t o2 = (size_t)4 * BB * DD * 4;
  u16*   ybf  = (u16*)(scratch + o2);                           // 0.5 MB
  o2 += (size_t)BB * DD * 2;
  float* zbuf = (float*)(scratch + o2);                         // 3 MB
  o2 += (size_t)BB * H3 * 4;
  float* zsq  = (float*)(scratch + o2);                         // 48 KB

  // prepass: convert & transpose
  k_f2b<<<dim3(2048), dim3(256), 0, stream>>>(x, xbf, BB * TT * EE / 4);
  k_transpose_f2b<<<dim3(DD / 32, (DD + EE) / 32, 1), dim3(256), 0, stream>>>(W_in, WT, DD + EE, DD);
  k_transpose_f2b<<<dim3(CH / 32, (DD / GG) / 32, GG), dim3(256), 0, stream>>>(W_blk, WbT, DD / GG, CH);
  k_initdet<<<dim3(BB * DD / 4 / 256), dim3(256), 0, stream>>>(deter0, dF, dB, BB * DD / 4);

  // P1: Xproj = x @ W2 + b_in   (M=4096, K=2048, N=4096); W2T rows at WT col-offset DD
  k_gemm<128, 128, 2, 2><<<dim3(DD / 128, BB * TT / 128, 1), dim3(256), 0, stream>>>(
      xbf, EE,
      WT + DD, DD + EE,
      Xproj, DD,
      b_in,
      EE);

  ScanPtrs SP;
  SP.WT = WT; SP.WbT = WbT; SP.Xproj = Xproj; SP.scale_in = scale_in;
  SP.b_blk = b_blk; SP.sblk = scale_blk; SP.part = part; SP.ybf = ybf;
  SP.zbuf = zbuf; SP.zsq = zsq; SP.dF = dF; SP.dB = dB; SP.out = out;

  void* args[] = {(void*)&SP};
  hipError_t cerr = hipLaunchCooperativeKernel(
      reinterpret_cast<void*>(&k_scan), dim3(256), dim3(512), args, 0, stream);
  if (cerr != hipSuccess) {
    // deterministic fallback: same phases as ordinary dispatches
    for (int t = 0; t < TT; t++) {
      kA<<<dim3(256), dim3(512), 0, stream>>>(SP);
      kB<<<dim3(BB), dim3(512), 0, stream>>>(SP, t);
      kC<<<dim3(192), dim3(512), 0, stream>>>(SP);
      kD<<<dim3(256), dim3(512), 0, stream>>>(SP, t);
    }
  }
}

// Round 4
// 1964.581 us; speedup vs baseline: 4.8368x; 4.8368x over previous
//
#include <hip/hip_runtime.h>

typedef unsigned short u16;
typedef unsigned int u32;
typedef __bf16 bfx8 __attribute__((ext_vector_type(8)));
typedef float f32x4 __attribute__((ext_vector_type(4)));

constexpr int BB = 64;     // batch
constexpr int TT = 64;     // time
constexpr int EE = 2048;   // x feature
constexpr int DD = 4096;   // deter
constexpr int GG = 8;      // groups
constexpr int H3 = 3 * DD;       // 12288
constexpr int CH = H3 / GG;      // 1536
constexpr float EPSf = 1e-4f;

static __device__ __forceinline__ u16 f2bf(float f) {
  u32 u = __builtin_bit_cast(u32, f);
  u32 r = (u + 0x7fffu + ((u >> 16) & 1u)) >> 16;
  return (u16)r;
}

// ---------------- prepass kernels ----------------

__global__ void __launch_bounds__(256) k_f2b(const float* __restrict__ in,
                                             u16* __restrict__ out, int n4) {
  int i = blockIdx.x * 256 + threadIdx.x;
  int stride = gridDim.x * 256;
  for (; i < n4; i += stride) {
    float4 v = ((const float4*)in)[i];
    uint2 o;
    o.x = (u32)f2bf(v.x) | ((u32)f2bf(v.y) << 16);
    o.y = (u32)f2bf(v.z) | ((u32)f2bf(v.w) << 16);
    ((uint2*)out)[i] = o;
  }
}

__global__ void __launch_bounds__(256) k_initdet(const float* __restrict__ d0,
                                                 float* __restrict__ dF,
                                                 u16* __restrict__ dB, int n4) {
  int i = blockIdx.x * 256 + threadIdx.x;
  if (i < n4) {
    float4 v = ((const float4*)d0)[i];
    ((float4*)dF)[i] = v;
    uint2 o;
    o.x = (u32)f2bf(v.x) | ((u32)f2bf(v.y) << 16);
    o.y = (u32)f2bf(v.z) | ((u32)f2bf(v.w) << 16);
    ((uint2*)dB)[i] = o;
  }
}

// in [R][C] f32 -> out [C][R] bf16  (batched over blockIdx.z)
__global__ void __launch_bounds__(256) k_transpose_f2b(const float* __restrict__ in,
                                                       u16* __restrict__ out,
                                                       int R, int C) {
  __shared__ float tile[32][33];
  size_t base = (size_t)blockIdx.z * R * C;
  in += base; out += base;
  int tx = threadIdx.x & 31, ty = threadIdx.x >> 5;
  int r0 = blockIdx.y * 32, c0 = blockIdx.x * 32;
#pragma unroll
  for (int i = 0; i < 4; i++) {
    int rr = ty * 4 + i;
    tile[rr][tx] = in[(size_t)(r0 + rr) * C + (c0 + tx)];
  }
  __syncthreads();
#pragma unroll
  for (int i = 0; i < 4; i++) {
    int cc = ty * 4 + i;
    out[(size_t)(c0 + cc) * R + (r0 + tx)] = f2bf(tile[tx][cc]);
  }
}

// ---------------- GEMM for P1 (Xproj): A[m][k] bf16 x B[n][k] bf16 -> C f32 ----------------

template<int BM, int BN, int WR, int WC>
__global__ void __launch_bounds__(256) k_gemm(
    const u16* __restrict__ A, int lda,
    const u16* __restrict__ B, int ldb,
    float* __restrict__ C, int ldc,
    const float* __restrict__ bias,
    int K) {
  constexpr int BK = 64, LS = BK + 8;
  constexpr int WTM = BM / WR, WTN = BN / WC, MF = WTM / 16, NF = WTN / 16;
  __shared__ u16 As[BM * LS];
  __shared__ u16 Bs[BN * LS];
  const int tid = threadIdx.x;
  const int m0 = blockIdx.y * BM, n0 = blockIdx.x * BN;
  const int w = tid >> 6, lane = tid & 63;
  const int wr = w / WC, wc = w % WC;
  const int lr = lane & 15, lk = (lane >> 4) * 8;

  f32x4 acc[MF][NF] = {};

  for (int kt = 0; kt < K; kt += BK) {
#pragma unroll
    for (int c = tid; c < BM * 8; c += 256) {
      int row = c >> 3, cc = c & 7;
      *(uint4*)&As[row * LS + cc * 8] =
          *(const uint4*)(A + (size_t)(m0 + row) * lda + kt + cc * 8);
    }
#pragma unroll
    for (int c = tid; c < BN * 8; c += 256) {
      int row = c >> 3, cc = c & 7;
      *(uint4*)&Bs[row * LS + cc * 8] =
          *(const uint4*)(B + (size_t)(n0 + row) * ldb + kt + cc * 8);
    }
    __syncthreads();
#pragma unroll
    for (int kk = 0; kk < BK; kk += 32) {
      bfx8 av[MF], bv[NF];
#pragma unroll
      for (int mi = 0; mi < MF; mi++)
        av[mi] = *(const bfx8*)&As[(wr * WTM + mi * 16 + lr) * LS + kk + lk];
#pragma unroll
      for (int ni = 0; ni < NF; ni++)
        bv[ni] = *(const bfx8*)&Bs[(wc * WTN + ni * 16 + lr) * LS + kk + lk];
#pragma unroll
      for (int mi = 0; mi < MF; mi++)
#pragma unroll
        for (int ni = 0; ni < NF; ni++)
          acc[mi][ni] = __builtin_amdgcn_mfma_f32_16x16x32_bf16(av[mi], bv[ni], acc[mi][ni], 0, 0, 0);
    }
    __syncthreads();
  }

  const int rq = (lane >> 4) * 4;
#pragma unroll
  for (int mi = 0; mi < MF; mi++) {
#pragma unroll
    for (int ni = 0; ni < NF; ni++) {
      int n = n0 + wc * WTN + ni * 16 + lr;
      float bias_v = bias ? bias[n] : 0.f;
#pragma unroll
      for (int r = 0; r < 4; r++) {
        int m = m0 + wr * WTM + mi * 16 + rq + r;
        C[(size_t)m * ldc + n] = acc[mi][ni][r] + bias_v;
      }
    }
  }
}

// ---------------- per-step kernels (wide, stream-ordered) ----------------
// kA: part[kc] = dB @ W1[:, kc-slice]   grid (64 n-tiles, 8 k-splits), 256 thr
__global__ void __launch_bounds__(256) kA(const u16* __restrict__ dB,
                                          const u16* __restrict__ WT,
                                          float* __restrict__ part) {
  constexpr int LS = 72;
  __shared__ u16 As[64 * LS];
  __shared__ u16 Bs[64 * LS];
  const int tid = threadIdx.x;
  const int n0 = blockIdx.x * 64;
  const int k0 = blockIdx.y * 512;
  const int w = tid >> 6, lane = tid & 63;
  const int lr = lane & 15, lk = (lane >> 4) * 8, rq = (lane >> 4) * 4;
  const int srow = tid >> 2, sc = (tid & 3) * 8;  // each thread: row srow, chunks sc and sc+32
  const u16* Arow = dB + (size_t)srow * DD + k0 + sc;
  const u16* Brow = WT + (size_t)(n0 + srow) * (DD + EE) + k0 + sc;

  f32x4 acc[4] = {};
  for (int kt = 0; kt < 512; kt += 64) {
    *(uint4*)&As[srow * LS + sc]      = *(const uint4*)(Arow + kt);
    *(uint4*)&As[srow * LS + sc + 32] = *(const uint4*)(Arow + kt + 32);
    *(uint4*)&Bs[srow * LS + sc]      = *(const uint4*)(Brow + kt);
    *(uint4*)&Bs[srow * LS + sc + 32] = *(const uint4*)(Brow + kt + 32);
    __syncthreads();
#pragma unroll
    for (int kk = 0; kk < 64; kk += 32) {
      bfx8 av = *(const bfx8*)&As[(w * 16 + lr) * LS + kk + lk];
#pragma unroll
      for (int ni = 0; ni < 4; ni++) {
        bfx8 bv = *(const bfx8*)&Bs[(ni * 16 + lr) * LS + kk + lk];
        acc[ni] = __builtin_amdgcn_mfma_f32_16x16x32_bf16(av, bv, acc[ni], 0, 0, 0);
      }
    }
    __syncthreads();
  }
  float* P = part + (size_t)blockIdx.y * BB * DD;
#pragma unroll
  for (int ni = 0; ni < 4; ni++)
#pragma unroll
    for (int r = 0; r < 4; r++)
      P[(size_t)(w * 16 + rq + r) * DD + n0 + ni * 16 + lr] = acc[ni][r];
}

// kB: y = silu(rms(sum_k part + Xproj_t) * scale_in) -> bf16   grid 64 (1/batch row)
__global__ void __launch_bounds__(256) kB(const float* __restrict__ part,
                                          const float* __restrict__ Xproj,
                                          const float* __restrict__ scale_in,
                                          u16* __restrict__ ybf, int t) {
  const int b = blockIdx.x, tid = threadIdx.x;
  const int w = tid >> 6, lane = tid & 63;
  __shared__ float sred[4];
  const float* xp = Xproj + ((size_t)b * TT + t) * DD;
  const float* pb = part + (size_t)b * DD;
  float4 v[4];
  float ss = 0.f;
#pragma unroll
  for (int j = 0; j < 4; j++) {
    const int col = j * 1024 + tid * 4;
    float4 a = *(const float4*)(xp + col);
#pragma unroll
    for (int kc = 0; kc < 8; kc++) {
      float4 p = *(const float4*)(pb + (size_t)kc * BB * DD + col);
      a.x += p.x; a.y += p.y; a.z += p.z; a.w += p.w;
    }
    v[j] = a;
    ss += a.x * a.x + a.y * a.y + a.z * a.z + a.w * a.w;
  }
#pragma unroll
  for (int o = 32; o > 0; o >>= 1) ss += __shfl_down(ss, o);
  if (lane == 0) sred[w] = ss;
  __syncthreads();
  const float r = rsqrtf((sred[0] + sred[1] + sred[2] + sred[3]) / (float)DD + EPSf);
#pragma unroll
  for (int j = 0; j < 4; j++) {
    const int col = j * 1024 + tid * 4;
    float4 sc4 = *(const float4*)(scale_in + col);
    float y0 = v[j].x * r * sc4.x, y1 = v[j].y * r * sc4.y;
    float y2 = v[j].z * r * sc4.z, y3 = v[j].w * r * sc4.w;
    y0 = y0 / (1.f + __expf(-y0)); y1 = y1 / (1.f + __expf(-y1));
    y2 = y2 / (1.f + __expf(-y2)); y3 = y3 / (1.f + __expf(-y3));
    uint2 o;
    o.x = (u32)f2bf(y0) | ((u32)f2bf(y1) << 16);
    o.y = (u32)f2bf(y2) | ((u32)f2bf(y3) << 16);
    *(uint2*)(ybf + (size_t)b * DD + col) = o;
  }
}

// kC: z = blockdiag(y @ Wblk) + b_blk -> zbuf f32; fused per-row sumsq -> zsq[192][64]
__global__ void __launch_bounds__(256) kC(const u16* __restrict__ ybf,
                                          const u16* __restrict__ WbT,
                                          const float* __restrict__ b_blk,
                                          float* __restrict__ zbuf,
                                          float* __restrict__ zsq) {
  constexpr int LS = 72;
  __shared__ u16 As[64 * LS];
  __shared__ u16 Bs[64 * LS];
  const int tid = threadIdx.x;
  const int wg = blockIdx.x;
  const int n0g = wg * 64;
  const int g = n0g / CH, nl = n0g % CH;
  const int w = tid >> 6, lane = tid & 63;
  const int lr = lane & 15, lk = (lane >> 4) * 8, rq = (lane >> 4) * 4;
  const int srow = tid >> 2, sc = (tid & 3) * 8;
  const u16* Arow = ybf + (size_t)srow * DD + g * (DD / GG) + sc;
  const u16* Brow = WbT + ((size_t)g * CH + nl + srow) * (DD / GG) + sc;

  f32x4 acc[4] = {};
  for (int kt = 0; kt < DD / GG; kt += 64) {
    *(uint4*)&As[srow * LS + sc]      = *(const uint4*)(Arow + kt);
    *(uint4*)&As[srow * LS + sc + 32] = *(const uint4*)(Arow + kt + 32);
    *(uint4*)&Bs[srow * LS + sc]      = *(const uint4*)(Brow + kt);
    *(uint4*)&Bs[srow * LS + sc + 32] = *(const uint4*)(Brow + kt + 32);
    __syncthreads();
#pragma unroll
    for (int kk = 0; kk < 64; kk += 32) {
      bfx8 av = *(const bfx8*)&As[(w * 16 + lr) * LS + kk + lk];
#pragma unroll
      for (int ni = 0; ni < 4; ni++) {
        bfx8 bv = *(const bfx8*)&Bs[(ni * 16 + lr) * LS + kk + lk];
        acc[ni] = __builtin_amdgcn_mfma_f32_16x16x32_bf16(av, bv, acc[ni], 0, 0, 0);
      }
    }
    __syncthreads();
  }
  float sq[4] = {0.f, 0.f, 0.f, 0.f};
#pragma unroll
  for (int ni = 0; ni < 4; ni++) {
    const int n = n0g + ni * 16 + lr;
    const float bias_v = b_blk[n];
#pragma unroll
    for (int r = 0; r < 4; r++) {
      const float zv = acc[ni][r] + bias_v;
      zbuf[(size_t)(w * 16 + rq + r) * H3 + n] = zv;
      sq[r] += zv * zv;
    }
  }
#pragma unroll
  for (int o = 1; o < 16; o <<= 1) {
#pragma unroll
    for (int r = 0; r < 4; r++) sq[r] += __shfl_xor(sq[r], o);
  }
  if (lr == 0) {
#pragma unroll
    for (int r = 0; r < 4; r++) zsq[(size_t)wg * 64 + w * 16 + rq + r] = sq[r];
  }
}

// kD: block-rms + gates + deter update + out write   grid 256 (= 64 b x 4 col-slices)
__global__ void __launch_bounds__(256) kD(const float* __restrict__ zbuf,
                                          const float* __restrict__ zsq,
                                          const float* __restrict__ sblk,
                                          float* __restrict__ dF,
                                          u16* __restrict__ dB,
                                          float* __restrict__ out, int t) {
  const int wg = blockIdx.x, tid = threadIdx.x;
  const int b = wg >> 2, s = wg & 3;
  __shared__ float sred[8];
  if (tid < 8) {
    float ssq = 0.f;
    const int j0 = tid * 24;
#pragma unroll
    for (int j = 0; j < 24; j++) ssq += zsq[(size_t)(j0 + j) * 64 + b];
    sred[tid] = rsqrtf(ssq / (float)CH + EPSf);
  }
  __syncthreads();
  const int d0 = s * 1024 + tid * 4;
  const float* zr = zbuf + (size_t)b * H3;
  float4 z0 = *(const float4*)(zr + d0);
  float4 z1 = *(const float4*)(zr + DD + d0);
  float4 z2 = *(const float4*)(zr + 2 * DD + d0);
  float4 dold = *(const float4*)(dF + (size_t)b * DD + d0);
  const float rsA = sred[d0 / CH];
  const float rsB = sred[(DD + d0) / CH];
  const float rsC = sred[(2 * DD + d0) / CH];
  float dn[4];
  const float* z0p = (const float*)&z0;
  const float* z1p = (const float*)&z1;
  const float* z2p = (const float*)&z2;
  const float* dop = (const float*)&dold;
#pragma unroll
  for (int e = 0; e < 4; e++) {
    const int dd = d0 + e;
    const float a0 = z0p[e] * rsA * sblk[dd];
    const float a1 = z1p[e] * rsB * sblk[DD + dd];
    const float a2 = z2p[e] * rsC * sblk[2 * DD + dd];
    const float reset = 1.f / (1.f + __expf(-a0));
    const float cand = tanhf(reset * a1);
    const float upd = 1.f / (1.f + __expf(-(a2 - 1.f)));
    dn[e] = upd * cand + (1.f - upd) * dop[e];
  }
  *(float4*)(dF + (size_t)b * DD + d0) = make_float4(dn[0], dn[1], dn[2], dn[3]);
  uint2 o;
  o.x = (u32)f2bf(dn[0]) | ((u32)f2bf(dn[1]) << 16);
  o.y = (u32)f2bf(dn[2]) | ((u32)f2bf(dn[3]) << 16);
  *(uint2*)(dB + (size_t)b * DD + d0) = o;
  *(float4*)(out + ((size_t)b * TT + t) * DD + d0) = make_float4(dn[0], dn[1], dn[2], dn[3]);
}

// ---------------- host ----------------

extern "C" void kernel_launch(void* const* d_in, const int* in_sizes, int n_in,
                              void* d_out, int out_size, void* d_ws, size_t ws_size,
                              hipStream_t stream) {
  (void)in_sizes; (void)n_in; (void)out_size; (void)ws_size;
  const float* x         = (const float*)d_in[0];  // [B,T,E]
  const float* deter0    = (const float*)d_in[1];  // [B,D]
  const float* W_in      = (const float*)d_in[2];  // [D+E, D]
  const float* b_in      = (const float*)d_in[3];  // [D]
  const float* scale_in  = (const float*)d_in[4];  // [D]
  const float* W_blk     = (const float*)d_in[5];  // [G, D/G, 3D/G]
  const float* b_blk     = (const float*)d_in[6];  // [3D]
  const float* scale_blk = (const float*)d_in[7];  // [G, 3D/G]
  float* out = (float*)d_out;

  char* ws = (char*)d_ws;
  size_t off = 0;
  auto alloc = [&](size_t bytes) -> void* {
    void* p = ws + off;
    off += (bytes + 255) & ~(size_t)255;
    return p;
  };
  u16*   WT    = (u16*)alloc((size_t)DD * (DD + EE) * 2);       // 50.3 MB
  u16*   WbT   = (u16*)alloc((size_t)GG * CH * (DD / GG) * 2);  // 12.6 MB
  float* Xproj = (float*)alloc((size_t)BB * TT * DD * 4);       // 64 MB
  float* dF    = (float*)alloc((size_t)BB * DD * 4);            // 1 MB
  u16*   dB    = (u16*)alloc((size_t)BB * DD * 2);              // 0.5 MB
  // scratch region: xbf (prepass/P1 only) aliases scan-only buffers
  char* scratch = (char*)alloc((size_t)BB * TT * EE * 2);       // 16.8 MB
  u16*   xbf  = (u16*)scratch;
  float* part = (float*)scratch;                                // 8 MB (8 splits)
  size_t o2 = (size_t)8 * BB * DD * 4;
  u16*   ybf  = (u16*)(scratch + o2);                           // 0.5 MB
  o2 += (size_t)BB * DD * 2;
  float* zbuf = (float*)(scratch + o2);                         // 3 MB
  o2 += (size_t)BB * H3 * 4;
  float* zsq  = (float*)(scratch + o2);                         // 48 KB

  // prepass: convert & transpose
  k_f2b<<<dim3(2048), dim3(256), 0, stream>>>(x, xbf, BB * TT * EE / 4);
  k_transpose_f2b<<<dim3(DD / 32, (DD + EE) / 32, 1), dim3(256), 0, stream>>>(W_in, WT, DD + EE, DD);
  k_transpose_f2b<<<dim3(CH / 32, (DD / GG) / 32, GG), dim3(256), 0, stream>>>(W_blk, WbT, DD / GG, CH);
  k_initdet<<<dim3(BB * DD / 4 / 256), dim3(256), 0, stream>>>(deter0, dF, dB, BB * DD / 4);

  // P1: Xproj = x @ W2 + b_in   (M=4096, K=2048, N=4096); W2T rows at WT col-offset DD
  k_gemm<128, 128, 2, 2><<<dim3(DD / 128, BB * TT / 128, 1), dim3(256), 0, stream>>>(
      xbf, EE,
      WT + DD, DD + EE,
      Xproj, DD,
      b_in,
      EE);

  for (int t = 0; t < TT; t++) {
    kA<<<dim3(64, 8), dim3(256), 0, stream>>>(dB, WT, part);
    kB<<<dim3(BB), dim3(256), 0, stream>>>(part, Xproj, scale_in, ybf, t);
    kC<<<dim3(192), dim3(256), 0, stream>>>(ybf, WbT, b_blk, zbuf, zsq);
    kD<<<dim3(256), dim3(256), 0, stream>>>(zbuf, zsq, scale_blk, dF, dB, out, t);
  }
}